// Round 6
// baseline (215.547 us; speedup 1.0000x reference)
//
#include <hip/hip_runtime.h>
#include <hip/hip_bf16.h>

// Sizes (fixed by the problem)
#define BB    8
#define DIMC  512
#define IMGS  32
#define NPIX  1024   // IMGS*IMGS
#define NHEAD 8
#define DHEAD 64

typedef __attribute__((ext_vector_type(8))) short short8;
typedef __attribute__((ext_vector_type(4))) float float4v;
typedef __attribute__((ext_vector_type(2))) _Float16 half2v;
typedef __attribute__((ext_vector_type(4))) _Float16 half4v;

__device__ __forceinline__ float b2f(unsigned short u) {
  union { unsigned int i; float f; } c;
  c.i = ((unsigned int)u) << 16;
  return c.f;
}
// fp32 -> bf16 bits, round-to-nearest-even
__device__ __forceinline__ unsigned short f2b(float f) {
  union { float f; unsigned int u; } c;
  c.f = f;
  unsigned int r = c.u + 0x7fffu + ((c.u >> 16) & 1u);
  return (unsigned short)(r >> 16);
}
// fp32 -> fp16 bits
__device__ __forceinline__ unsigned short f2h(float f) {
  union { _Float16 h; unsigned short u; } c;
  c.h = (_Float16)f;
  return c.u;
}

__device__ __forceinline__ void storeC(float* p, float v) { *p = v; }
__device__ __forceinline__ void storeC(unsigned short* p, float v) { *p = f2b(v); }

// async global -> LDS, 16 bytes per lane. LDS dest must be wave-uniform base
// + lane*16 (HW constraint) — all call sites below satisfy that.
__device__ __forceinline__ void async16(const void* g, void* l) {
  __builtin_amdgcn_global_load_lds(
      (const __attribute__((address_space(1))) void*)g,
      (__attribute__((address_space(3))) void*)l, 16, 0, 0);
}

// ---------------------------------------------------------------------------
// Kernel 0: weight prep.
//  (a) pw_w (3*512*512) and out_w (512*512) fp32 -> bf16; q block (first
//      512*512) pre-scaled by 0.125 (=DH^-0.5). Scaled bias bb[3*512].
//  (b) depthwise prep: wT[i][tap][512] = dw_w[i][c][tap] * bnscale[i][c],
//      shiftv[i][512] = (dw_b - bn_m)*bnscale + bn_b  (BN folded into conv).
// ---------------------------------------------------------------------------
__global__ __launch_bounds__(256) void wcvt_kernel(
    const float* __restrict__ pw_w, const float* __restrict__ out_w,
    const float* __restrict__ pw_b, const float* __restrict__ dw_w,
    const float* __restrict__ dw_b, const float* __restrict__ bn_g,
    const float* __restrict__ bn_b, const float* __restrict__ bn_m,
    const float* __restrict__ bn_v, unsigned short* __restrict__ wbf,
    float* __restrict__ bb, float* __restrict__ wT,
    float* __restrict__ shiftv) {
  const int i4 = (blockIdx.x * 256 + threadIdx.x) * 4;
  float4 v = (i4 < 3 * DIMC * DIMC)
                 ? *reinterpret_cast<const float4*>(pw_w + i4)
                 : *reinterpret_cast<const float4*>(out_w + (i4 - 3 * DIMC * DIMC));
  const float sc = (i4 < DIMC * DIMC) ? 0.125f : 1.0f;
  ushort4 o;
  o.x = f2b(v.x * sc); o.y = f2b(v.y * sc); o.z = f2b(v.z * sc); o.w = f2b(v.w * sc);
  *reinterpret_cast<ushort4*>(wbf + i4) = o;
  const int idx = blockIdx.x * 256 + threadIdx.x;
  if (idx < 6 * 256) {
    if (idx < 3 * DIMC / 2) {
      #pragma unroll
      for (int hh = 0; hh < 2; ++hh) {
        const int id2 = idx * 2 + hh;  // (i,c) pair, i=id2/512, c=id2%512
        const int i = id2 >> 9, c = id2 & 511;
        const float scale = bn_g[id2] * rsqrtf(bn_v[id2] + 1e-5f);
        shiftv[id2] = (dw_b[id2] - bn_m[id2]) * scale + bn_b[id2];
        #pragma unroll
        for (int t = 0; t < 9; ++t)
          wT[(i * 9 + t) * DIMC + c] = dw_w[(size_t)id2 * 9 + t] * scale;
      }
    }
    if (idx < 3 * DIMC)
      bb[idx] = pw_b[idx] * (idx < DIMC ? 0.125f : 1.0f);
  }
}

// ---------------------------------------------------------------------------
// Kernel 1: depthwise 3x3 + folded BN for all 3 projections.
// Thread: 4 output rows x 1 pixel-col x 4 channels x 3 projections.
// ---------------------------------------------------------------------------
__global__ __launch_bounds__(256) void dwbn_kernel(
    const float* __restrict__ x, const float* __restrict__ wT,
    const float* __restrict__ shiftv, unsigned short* __restrict__ z) {
  const int wp = blockIdx.x, lg = blockIdx.y, b = blockIdx.z;
  const int t = threadIdx.x;
  const int c = (t & 127) * 4;
  const int w = wp * 2 + (t >> 7);
  const int l0 = lg * 4;
  const float* xb = x + (size_t)b * NPIX * DIMC + c;

  const float4 zero4 = make_float4(0.f, 0.f, 0.f, 0.f);
  float4 win[6][3];
  #pragma unroll
  for (int rr = 0; rr < 6; ++rr) {
    const int l = l0 - 1 + rr;
    #pragma unroll
    for (int dw = 0; dw < 3; ++dw) {
      const int ww = w - 1 + dw;
      const bool ok = ((unsigned)l < IMGS) && ((unsigned)ww < IMGS);
      win[rr][dw] = ok ? *reinterpret_cast<const float4*>(
                             xb + (size_t)(l * IMGS + ww) * DIMC)
                       : zero4;
    }
  }

  #pragma unroll
  for (int i = 0; i < 3; ++i) {
    float4 wv[9];
    #pragma unroll
    for (int tp = 0; tp < 9; ++tp)
      wv[tp] = *reinterpret_cast<const float4*>(wT + (i * 9 + tp) * DIMC + c);
    const float4 sh = *reinterpret_cast<const float4*>(shiftv + i * DIMC + c);
    #pragma unroll
    for (int r = 0; r < 4; ++r) {
      float a0 = sh.x, a1 = sh.y, a2 = sh.z, a3 = sh.w;
      #pragma unroll
      for (int kh = 0; kh < 3; ++kh)
        #pragma unroll
        for (int kw = 0; kw < 3; ++kw) {
          const float4 wq = wv[kh * 3 + kw];
          const float4 xq = win[r + kh][kw];
          a0 = fmaf(wq.x, xq.x, a0);
          a1 = fmaf(wq.y, xq.y, a1);
          a2 = fmaf(wq.z, xq.z, a2);
          a3 = fmaf(wq.w, xq.w, a3);
        }
      ushort4 st;
      st.x = f2b(a0); st.y = f2b(a1); st.z = f2b(a2); st.w = f2b(a3);
      *reinterpret_cast<ushort4*>(
          z + (((size_t)(i * BB + b)) * NPIX + (l0 + r) * IMGS + w) * DIMC + c) = st;
    }
  }
}

// ---------------------------------------------------------------------------
// Kernel 2: MFMA GEMM  C[m][n] = sum_k A[m][k]*W[n][k] + bias[n]
// 128x128 tile, BK=32, 4 waves (2x2), 16x16x32 bf16 MFMA, frag-order LDS.
// ---------------------------------------------------------------------------
template <typename CT>
__global__ __launch_bounds__(256) void gemm_mfma(
    const unsigned short* __restrict__ Abase,
    const unsigned short* __restrict__ Wbase,
    const float* __restrict__ biasBase, CT* __restrict__ Cbase) {
  __shared__ short As[8 * 64 * 8];  // 8 KB
  __shared__ short Bs[8 * 64 * 8];  // 8 KB
  const int bz = blockIdx.z;
  const int wi = bz >> 3;
  const short* A = (const short*)Abase + (size_t)bz * NPIX * DIMC;
  const short* W = (const short*)Wbase + (size_t)wi * DIMC * DIMC;
  const float* bias = biasBase + wi * DIMC;
  CT* C = Cbase + (size_t)bz * NPIX * DIMC;

  const int t = threadIdx.x;
  const int wv = t >> 6, lane = t & 63;
  const int lo = lane & 15, hi = lane >> 4;
  const int wm = wv >> 1, wn = wv & 1;
  const int m0 = blockIdx.y * 128, n0 = blockIdx.x * 128;

  float4v acc[4][4];
  #pragma unroll
  for (int i = 0; i < 4; ++i)
    #pragma unroll
    for (int j = 0; j < 4; ++j) acc[i][j] = {0.f, 0.f, 0.f, 0.f};

  for (int k0 = 0; k0 < DIMC; k0 += 32) {
    #pragma unroll
    for (int p = 0; p < 2; ++p) {
      const int sub = wv + p * 4;
      async16(A + (size_t)(m0 + sub * 16 + lo) * DIMC + k0 + hi * 8,
              As + (sub * 64 + lane) * 8);
      async16(W + (size_t)(n0 + sub * 16 + lo) * DIMC + k0 + hi * 8,
              Bs + (sub * 64 + lane) * 8);
    }
    __syncthreads();
    short8 af[4], bf[4];
    #pragma unroll
    for (int mt = 0; mt < 4; ++mt)
      af[mt] = *reinterpret_cast<const short8*>(As + ((wm * 4 + mt) * 64 + lane) * 8);
    #pragma unroll
    for (int nt = 0; nt < 4; ++nt)
      bf[nt] = *reinterpret_cast<const short8*>(Bs + ((wn * 4 + nt) * 64 + lane) * 8);
    #pragma unroll
    for (int mt = 0; mt < 4; ++mt)
      #pragma unroll
      for (int nt = 0; nt < 4; ++nt)
        acc[mt][nt] = __builtin_amdgcn_mfma_f32_16x16x32_bf16(af[mt], bf[nt],
                                                              acc[mt][nt], 0, 0, 0);
    __syncthreads();
  }

  float bv[4];
  #pragma unroll
  for (int nt = 0; nt < 4; ++nt) bv[nt] = bias[n0 + wn * 64 + nt * 16 + lo];
  #pragma unroll
  for (int mt = 0; mt < 4; ++mt) {
    #pragma unroll
    for (int r = 0; r < 4; ++r) {
      const int row = m0 + wm * 64 + mt * 16 + hi * 4 + r;
      CT* cp = C + (size_t)row * DIMC + n0 + wn * 64 + lo;
      #pragma unroll
      for (int nt = 0; nt < 4; ++nt) storeC(cp + nt * 16, acc[mt][nt][r] + bv[nt]);
    }
  }
}

// ---------------------------------------------------------------------------
// Kernel 3: transpose V -> VT[b][h][d(64)][n(1024)] as FP16 (PV runs in f16
// MFMA). 64x64 LDS tile per block.
// ---------------------------------------------------------------------------
__global__ __launch_bounds__(256) void vt_kernel(
    const unsigned short* __restrict__ v, unsigned short* __restrict__ vt) {
  __shared__ unsigned short tile[64][68];
  const int n0 = blockIdx.x * 64, h = blockIdx.y, b = blockIdx.z;
  const int t = threadIdx.x;
  const unsigned short* vb = v + (size_t)b * NPIX * DIMC + h * DHEAD;
  #pragma unroll
  for (int u = 0; u < 4; ++u) {
    const int lin = t + u * 256;
    const int row = lin >> 4, c4 = (lin & 15) * 4;
    *reinterpret_cast<ushort4*>(&tile[row][c4]) =
        *reinterpret_cast<const ushort4*>(vb + (size_t)(n0 + row) * DIMC + c4);
  }
  __syncthreads();
  unsigned short* vtb = vt + ((size_t)(b * NHEAD + h)) * DHEAD * NPIX;
  #pragma unroll
  for (int u = 0; u < 4; ++u) {
    const int lin = t + u * 256;
    const int d = lin >> 4, n4 = (lin & 15) * 4;
    ushort4 o;
    o.x = f2h(b2f(tile[n4 + 0][d]));
    o.y = f2h(b2f(tile[n4 + 1][d]));
    o.z = f2h(b2f(tile[n4 + 2][d]));
    o.w = f2h(b2f(tile[n4 + 3][d]));
    *reinterpret_cast<ushort4*>(vtb + (size_t)d * NPIX + n0 + n4) = o;
  }
}

// ---------------------------------------------------------------------------
// Kernel 4: register-resident MFMA attention (no LDS in the K-loop).
// Block = (b, h, qt) [XCD = b for L2 locality]; 64 q-rows; wave w owns
// k-columns [w*256, w*256+256) in 16-col tiles.
// Operand-swap trick: S^T = K·Q^T via mfma_16x16x32_bf16(A=Kfrag, B=Qfrag)
// puts S[q=lo][k=hi*4+r] in registers == the A-layout of mfma_16x16x16_f16.
// So P = exp(S) goes exp -> cvt_pkrtz(f16) -> PV MFMA with zero LDS traffic.
// K/VT frags load straight from global (16B / 8B contiguous per lane).
// Cross-wave O/l reduction at the end through 17.7 KB LDS.
// ---------------------------------------------------------------------------
__global__ __launch_bounds__(256, 3) void attn_mfma(
    const unsigned short* __restrict__ qkv, const unsigned short* __restrict__ vt,
    unsigned short* __restrict__ attn_o) {
  __shared__ char sm[17664];  // Obuf 16K | lbuf 1K | linv 256B
  const int b = blockIdx.x, h = blockIdx.y, qt = blockIdx.z;
  const int t = threadIdx.x;
  const int wv = t >> 6, lane = t & 63;
  const int lo = lane & 15, hi = lane >> 4;

  const short* qb = (const short*)qkv + ((size_t)(0 * BB + b) * NPIX) * DIMC + h * DHEAD;
  const short* kb = (const short*)qkv + ((size_t)(1 * BB + b) * NPIX) * DIMC + h * DHEAD;
  const _Float16* vth =
      (const _Float16*)vt + ((size_t)(b * NHEAD + h)) * DHEAD * NPIX;

  // Q frags (used as MFMA B-operand; layout identical to A-frag load)
  short8 qf[4][2];
  #pragma unroll
  for (int mt = 0; mt < 4; ++mt)
    #pragma unroll
    for (int cc = 0; cc < 2; ++cc)
      qf[mt][cc] = *reinterpret_cast<const short8*>(
          qb + (size_t)(qt * 64 + mt * 16 + lo) * DIMC + cc * 32 + hi * 8);

  float4v oacc[4][4];
  float lsumv[4] = {0.f, 0.f, 0.f, 0.f};
  #pragma unroll
  for (int mt = 0; mt < 4; ++mt)
    #pragma unroll
    for (int dt = 0; dt < 4; ++dt) oacc[mt][dt] = {0.f, 0.f, 0.f, 0.f};

  const int kw0 = wv * 256;  // this wave's private k-column strip
  for (int it = 0; it < 16; ++it) {
    const int k0 = kw0 + it * 16;
    // K frags: K[k0+lo][cc*32 + hi*8 ..+7]  (16B contiguous per lane)
    const short8 kf0 =
        *reinterpret_cast<const short8*>(kb + (size_t)(k0 + lo) * DIMC + hi * 8);
    const short8 kf1 =
        *reinterpret_cast<const short8*>(kb + (size_t)(k0 + lo) * DIMC + 32 + hi * 8);
    // VT f16 frags: VT[dt*16+lo][k0 + hi*4 ..+3]  (8B contiguous per lane)
    half4v vf[4];
    #pragma unroll
    for (int dt = 0; dt < 4; ++dt)
      vf[dt] = *reinterpret_cast<const half4v*>(
          vth + (size_t)(dt * 16 + lo) * NPIX + k0 + hi * 4);

    // S^T = K Q^T : lane gets S[q=lo][k = k0 + hi*4 + r]
    float4v sacc[4];
    #pragma unroll
    for (int mt = 0; mt < 4; ++mt) {
      sacc[mt] = {0.f, 0.f, 0.f, 0.f};
      sacc[mt] = __builtin_amdgcn_mfma_f32_16x16x32_bf16(kf0, qf[mt][0], sacc[mt], 0, 0, 0);
      sacc[mt] = __builtin_amdgcn_mfma_f32_16x16x32_bf16(kf1, qf[mt][1], sacc[mt], 0, 0, 0);
    }

    // P = exp(S) -> f16 A-frags; accumulate l per q-row (=lo)
    half4v pf[4];
    #pragma unroll
    for (int mt = 0; mt < 4; ++mt) {
      const float p0 = __expf(sacc[mt][0]);
      const float p1 = __expf(sacc[mt][1]);
      const float p2 = __expf(sacc[mt][2]);
      const float p3 = __expf(sacc[mt][3]);
      lsumv[mt] += (p0 + p1) + (p2 + p3);
      const half2v a01 =
          __builtin_bit_cast(half2v, __builtin_amdgcn_cvt_pkrtz(p0, p1));
      const half2v a23 =
          __builtin_bit_cast(half2v, __builtin_amdgcn_cvt_pkrtz(p2, p3));
      pf[mt] = half4v{a01[0], a01[1], a23[0], a23[1]};
    }

    // O += P V  (16x16x16 f16 MFMA; A=P regs, B=VT frags)
    #pragma unroll
    for (int mt = 0; mt < 4; ++mt)
      #pragma unroll
      for (int dt = 0; dt < 4; ++dt)
        oacc[mt][dt] = __builtin_amdgcn_mfma_f32_16x16x16f16(pf[mt], vf[dt],
                                                             oacc[mt][dt], 0, 0, 0);
  }

  // l partials: lane holds partial sum for q-row lo over its hi-quad's k.
  // Reduce across quads (lanes differing in hi).
  #pragma unroll
  for (int mt = 0; mt < 4; ++mt) {
    float v = lsumv[mt];
    v += __shfl_xor(v, 16);
    v += __shfl_xor(v, 32);
    lsumv[mt] = v;
  }

  float* Obuf = (float*)sm;             // 16 KB
  float* lbuf = (float*)(sm + 16384);   // 4*64 f32
  float* linv = (float*)(sm + 17408);   // 64 f32
  if (hi == 0) {
    #pragma unroll
    for (int mt = 0; mt < 4; ++mt) lbuf[wv * 64 + mt * 16 + lo] = lsumv[mt];
  }
  __syncthreads();
  if (t < 64) linv[t] = 1.0f / (lbuf[t] + lbuf[64 + t] + lbuf[128 + t] + lbuf[192 + t]);

  unsigned short* aob = attn_o + ((size_t)b * NPIX + qt * 64) * DIMC + h * DHEAD;
  #pragma unroll
  for (int mt = 0; mt < 4; ++mt) {
    __syncthreads();
    #pragma unroll
    for (int dt = 0; dt < 4; ++dt)
      #pragma unroll
      for (int r = 0; r < 4; ++r)
        Obuf[wv * 1024 + (dt * 4 + r) * 64 + lane] = oacc[mt][dt][r];
    __syncthreads();
    #pragma unroll
    for (int k2 = 0; k2 < 4; ++k2) {
      const int e = t + k2 * 256;
      const float sum2 = Obuf[e] + Obuf[1024 + e] + Obuf[2048 + e] + Obuf[3072 + e];
      const int dt = e >> 8, r = (e >> 6) & 3, le = e & 63;
      const int row = mt * 16 + (le >> 4) * 4 + r, d = dt * 16 + (le & 15);
      aob[(size_t)row * DIMC + d] = f2b(sum2 * linv[row]);
    }
  }
}

// ---------------------------------------------------------------------------
extern "C" void kernel_launch(void* const* d_in, const int* in_sizes, int n_in,
                              void* d_out, int out_size, void* d_ws, size_t ws_size,
                              hipStream_t stream) {
  const float* x    = (const float*)d_in[0];
  const float* dw_w = (const float*)d_in[1];
  const float* dw_b = (const float*)d_in[2];
  const float* bn_g = (const float*)d_in[3];
  const float* bn_b = (const float*)d_in[4];
  const float* bn_m = (const float*)d_in[5];
  const float* bn_v = (const float*)d_in[6];
  const float* pw_w = (const float*)d_in[7];
  const float* pw_b = (const float*)d_in[8];
  const float* out_w = (const float*)d_in[9];
  const float* out_b = (const float*)d_in[10];
  float* out = (float*)d_out;

  // Workspace layout (16-bit elements unless noted):
  //   z      [3][B][N][512] bf16  (25.2 MB)
  //   qkv    [3][B][N][512] bf16  (25.2 MB)
  //   wbf    pw_w|out_w bf16      ( 2.1 MB)
  //   bb/wT/shiftv small f32
  // After the qkv GEMM, z is dead: VT-f16 (8.4MB) and attn_o (8.4MB) overlay.
  unsigned short* z   = (unsigned short*)d_ws;
  unsigned short* qkv = z + (size_t)3 * BB * NPIX * DIMC;
  unsigned short* wbf = qkv + (size_t)3 * BB * NPIX * DIMC;
  float* bb = (float*)(wbf + (size_t)4 * DIMC * DIMC);
  float* wT = bb + 3 * DIMC;
  float* shiftv = wT + 3 * 9 * DIMC;
  unsigned short* vtb = z;
  unsigned short* attn_o = z + (size_t)BB * NHEAD * DHEAD * NPIX;

  wcvt_kernel<<<dim3(1024), 256, 0, stream>>>(pw_w, out_w, pw_b, dw_w, dw_b,
                                              bn_g, bn_b, bn_m, bn_v, wbf, bb,
                                              wT, shiftv);
  dwbn_kernel<<<dim3(16, 8, BB), 256, 0, stream>>>(x, wT, shiftv, z);
  // qkv = z * pw_w^T + bb  (24 batches, W index = batch>>3; q pre-scaled)
  gemm_mfma<unsigned short><<<dim3(4, 8, 24), 256, 0, stream>>>(z, wbf, bb, qkv);
  // VT (f16) for the PV B-operand
  vt_kernel<<<dim3(16, NHEAD, BB), 256, 0, stream>>>(
      qkv + (size_t)2 * BB * NPIX * DIMC, vtb);
  // attention — grid ordered (b, h, qt) so XCD = b (K/V stay in one L2)
  attn_mfma<<<dim3(BB, NHEAD, 16), 256, 0, stream>>>(qkv, vtb, attn_o);
  // out = attn_o * out_w^T + out_b (8 batches, single W at wbf+786432)
  gemm_mfma<float><<<dim3(4, 8, 8), 256, 0, stream>>>(
      attn_o, wbf + (size_t)3 * DIMC * DIMC, out_b, out);
}